// Round 16
// baseline (330.384 us; speedup 1.0000x reference)
//
#include <hip/hip_runtime.h>
#include <hip/hip_bf16.h>
#include <math.h>

#define B_    2
#define L_    4096
#define DM    1024
#define DI    2048
#define DS    128
#define NH    32
#define HD    64
#define CHUNK 64
#define NC    (L_/CHUNK)          // 64
#define CD    (DI + 2*DS)         // 2304
#define ROWS  (B_*L_)             // 8192
#define NOUT  (2*DI + 2*DS + NH)  // 4384
#define NPAD2 4608                // conversion pad

typedef __attribute__((ext_vector_type(4))) float f32x4;
typedef __attribute__((ext_vector_type(8))) __bf16 bf16x8;
typedef __attribute__((ext_vector_type(4))) short s16x4;
typedef __attribute__((ext_vector_type(8))) short s16x8;

// ---------------- fused conversion kernel (u, W_in(pad), W_out) ----------------
__global__ __launch_bounds__(256) void k_convert_all(const float* __restrict__ u, const float* __restrict__ W_in,
                                                     const float* __restrict__ W_out, __bf16* __restrict__ ubf,
                                                     __bf16* __restrict__ wibf, __bf16* __restrict__ wobf) {
    int i = blockIdx.x * 256 + threadIdx.x;
    const int QU  = ROWS * DM / 4;
    const int QWI = NPAD2 * DM / 4;
    const int QWO = DM * DI / 4;
    const float* s = nullptr;
    __bf16* d;
    bool zero = false;
    if (i < QU) {
        s = u + (size_t)i * 4; d = ubf + (size_t)i * 4;
    } else if (i < QU + QWI) {
        int j = i - QU;
        d = wibf + (size_t)j * 4;
        if (j < NOUT * DM / 4) s = W_in + (size_t)j * 4; else zero = true;
    } else if (i < QU + QWI + QWO) {
        int j = i - QU - QWI;
        s = W_out + (size_t)j * 4; d = wobf + (size_t)j * 4;
    } else return;
    s16x4 o = {0, 0, 0, 0};
    if (!zero) {
        f32x4 v = *(const f32x4*)s;
#pragma unroll
        for (int q = 0; q < 4; q++) o[q] = __builtin_bit_cast(short, (__bf16)v[q]);
    }
    *(s16x4*)d = o;
}

// ---------------- staging / frag-read helpers (T2 swizzle, proven 0-conflict) ----------------
__device__ __forceinline__ void stage_half(const __bf16* __restrict__ G, int ldg, int grow0, int kt,
                                           char* lds, int ldsoff, int tid, int wave) {
#pragma unroll
    for (int issue = 0; issue < 2; issue++) {
        int o   = issue * 8192 + tid * 16;
        int row = o >> 7;
        int cb  = (o & 127) ^ ((row & 7) << 4);
        const __bf16* src = G + (size_t)(grow0 + row) * ldg + kt + (cb >> 1);
        char* ldsbase = lds + ldsoff + issue * 8192 + wave * 1024;
        __builtin_amdgcn_global_load_lds((const __attribute__((address_space(1))) void*)src,
                                         (__attribute__((address_space(3))) void*)ldsbase,
                                         16, 0, 0);
    }
}

__device__ __forceinline__ bf16x8 rdfrag(const char* lds, int ldsoff, int r, int ks, int lane) {
    int logical = r * 128 + ks * 64 + ((lane >> 4) << 4);
    int phys    = logical ^ ((r & 7) << 4);
    return *(const bf16x8*)(lds + ldsoff + phys);
}

// =====================================================================
// 128x128 GEMM core, BK=64, 8 waves, SINGLE-buffered 32 KiB LDS ->
// 4 blocks/CU (m97/m114 cross-block mechanism). min-waves stays 4 (r12).
// =====================================================================
__device__ __forceinline__ void gemm128x128_core(const __bf16* __restrict__ Ag, const __bf16* __restrict__ Bg,
                                                 int K, int m0, int n0, char* lds, f32x4 acc[4][2]) {
    const int tid = threadIdx.x, wave = tid >> 6, lane = tid & 63;
    const int wm = wave >> 2, wn = wave & 3, lrow = lane & 15;
    const int KT = K >> 6;

    for (int t = 0; t < KT; t++) {
        const int kt = t << 6;
        stage_half(Ag, K, m0, kt, lds, 0,     tid, wave);
        stage_half(Bg, K, n0, kt, lds, 16384, tid, wave);
        asm volatile("s_waitcnt vmcnt(0)" ::: "memory");
        __builtin_amdgcn_s_barrier();
        bf16x8 a[4][2];
#pragma unroll
        for (int fm = 0; fm < 4; fm++)
#pragma unroll
            for (int ks = 0; ks < 2; ks++)
                a[fm][ks] = rdfrag(lds, 0, wm * 64 + fm * 16 + lrow, ks, lane);
        __builtin_amdgcn_s_setprio(1);
#pragma unroll
        for (int fn = 0; fn < 2; fn++) {
            bf16x8 b0 = rdfrag(lds, 16384, wn * 32 + fn * 16 + lrow, 0, lane);
            bf16x8 b1 = rdfrag(lds, 16384, wn * 32 + fn * 16 + lrow, 1, lane);
#pragma unroll
            for (int fm = 0; fm < 4; fm++) {
                acc[fm][fn] = __builtin_amdgcn_mfma_f32_16x16x32_bf16(a[fm][0], b0, acc[fm][fn], 0, 0, 0);
                acc[fm][fn] = __builtin_amdgcn_mfma_f32_16x16x32_bf16(a[fm][1], b1, acc[fm][fn], 0, 0, 0);
            }
        }
        __builtin_amdgcn_s_setprio(0);
        __builtin_amdgcn_s_barrier();
    }
}

// GEMM1: zxbcdt = u @ W_in^T, fused split + softplus epilogue.
__global__ __launch_bounds__(512, 4) void k_gemm1(const __bf16* __restrict__ ubf, const __bf16* __restrict__ wibf,
                                                  __bf16* __restrict__ zbuf, __bf16* __restrict__ xbcraw,
                                                  float* __restrict__ dtbuf, const float* __restrict__ dt_bias) {
    extern __shared__ char lds[];
    f32x4 acc[4][2];
    f32x4 z4 = {0.f, 0.f, 0.f, 0.f};
#pragma unroll
    for (int i = 0; i < 4; i++)
#pragma unroll
        for (int j = 0; j < 2; j++) acc[i][j] = z4;

    int bid = blockIdx.x;
    int wg  = (bid & 7) * 280 + (bid >> 3);    // 2240 wgs, bijective
    int m0  = (wg / 35) * 128;
    int n0  = (wg % 35) * 128;
    gemm128x128_core(ubf, wibf, DM, m0, n0, lds, acc);

    const int lane = threadIdx.x & 63, wave = threadIdx.x >> 6;
    const int wm = wave >> 2, wn = wave & 3;
    const int gm_base = m0 + wm * 64 + ((lane >> 4) << 2);
    const int gn_base = n0 + wn * 32 + (lane & 15);
#pragma unroll
    for (int fm = 0; fm < 4; fm++) {
        const int gmb = gm_base + fm * 16;
#pragma unroll
        for (int fn = 0; fn < 2; fn++) {
            const int gn = gn_base + fn * 16;
            if (gn < DI) {
#pragma unroll
                for (int r = 0; r < 4; r++)
                    zbuf[(size_t)(gmb + r) * DI + gn] = (__bf16)acc[fm][fn][r];
            } else if (gn < DI + CD) {
#pragma unroll
                for (int r = 0; r < 4; r++)
                    xbcraw[(size_t)(gmb + r) * CD + (gn - DI)] = (__bf16)acc[fm][fn][r];
            } else if (gn < NOUT) {
                const int hh = gn - (DI + CD);
                const float bb = dt_bias[hh];
#pragma unroll
                for (int r = 0; r < 4; r++) {
                    float x = acc[fm][fn][r] + bb;
                    float sp = (x > 20.f) ? x : log1pf(__expf(x));
                    dtbuf[(size_t)(gmb + r) * NH + hh] = sp;
                }
            }
        }
    }
}

// GEMM2 (fallback): out = ynorm @ W_out^T
__global__ __launch_bounds__(512, 4) void k_gemm2(const __bf16* __restrict__ ybf, const __bf16* __restrict__ wobf,
                                                  float* __restrict__ out) {
    extern __shared__ char lds[];
    f32x4 acc[4][2];
    f32x4 z4 = {0.f, 0.f, 0.f, 0.f};
#pragma unroll
    for (int i = 0; i < 4; i++)
#pragma unroll
        for (int j = 0; j < 2; j++) acc[i][j] = z4;

    int bid = blockIdx.x;
    int wg  = (bid & 7) * 64 + (bid >> 3);     // 512 wgs, bijective
    int m0  = (wg / 8) * 128;
    int n0  = (wg % 8) * 128;
    gemm128x128_core(ybf, wobf, DI, m0, n0, lds, acc);

    const int lane = threadIdx.x & 63, wave = threadIdx.x >> 6;
    const int wm = wave >> 2, wn = wave & 3;
    const int gm_base = m0 + wm * 64 + ((lane >> 4) << 2);
    const int gn_base = n0 + wn * 32 + (lane & 15);
#pragma unroll
    for (int fm = 0; fm < 4; fm++) {
        const int gmb = gm_base + fm * 16;
#pragma unroll
        for (int fn = 0; fn < 2; fn++) {
            const int gn = gn_base + fn * 16;
#pragma unroll
            for (int r = 0; r < 4; r++)
                out[(size_t)(gmb + r) * DM + gn] = acc[fm][fn][r];
        }
    }
}

// =====================================================================
// GEMM2-FUSED: out = rms[m] * ((y*silu(z)*norm_w) @ W_out^T)
// A staged via reg-compute + swizzled ds_write; per-row sum(g^2)
// accumulated across K, reduced in 8-lane groups, rms applied in epilogue.
// LDS: A 16K @0 (swizzled), B 16K @16384 (gload_lds), rmsh 512B @32768.
// =====================================================================
__global__ __launch_bounds__(512, 4) void k_gemm2f(const __bf16* __restrict__ ybuf, const __bf16* __restrict__ zbuf,
                                                   const float* __restrict__ norm_w, const __bf16* __restrict__ wobf,
                                                   float* __restrict__ out) {
    extern __shared__ char lds[];
    const int tid = threadIdx.x, wave = tid >> 6, lane = tid & 63;
    const int wm = wave >> 2, wn = wave & 3, lrow = lane & 15;

    f32x4 acc[4][2];
    f32x4 z4 = {0.f, 0.f, 0.f, 0.f};
#pragma unroll
    for (int i = 0; i < 4; i++)
#pragma unroll
        for (int j = 0; j < 2; j++) acc[i][j] = z4;

    int bid = blockIdx.x;
    int wg  = (bid & 7) * 64 + (bid >> 3);     // 512 wgs, bijective
    int m0  = (wg / 8) * 128;
    int n0  = (wg % 8) * 128;

    const int rA = tid >> 3;                    // rows this thread stages
    float ssA = 0.f, ssB = 0.f;                 // sum(g^2) partials

    for (int t = 0; t < 32; t++) {              // K = 2048, BK = 64
        const int kt = t << 6;
        // B tile: normal gload_lds path
        stage_half(wobf, DI, n0, kt, lds, 16384, tid, wave);
        // A tile: gate + scale, swizzled ds_write
#pragma unroll
        for (int issue = 0; issue < 2; issue++) {
            const int o    = issue * 8192 + tid * 16;
            const int row  = o >> 7;
            const int colb = o & 127;
            const int col  = kt + (colb >> 1);
            const __bf16* yp = ybuf + (size_t)(m0 + row) * DI + col;
            const __bf16* zp = zbuf + (size_t)(m0 + row) * DI + col;
            s16x8 y8 = *(const s16x8*)yp;
            s16x8 z8 = *(const s16x8*)zp;
            f32x4 nw0 = *(const f32x4*)(norm_w + col);
            f32x4 nw1 = *(const f32x4*)(norm_w + col + 4);
            float ssl = 0.f;
            s16x8 a8;
#pragma unroll
            for (int j = 0; j < 8; j++) {
                float y = (float)__builtin_bit_cast(__bf16, (short)y8[j]);
                float z = (float)__builtin_bit_cast(__bf16, (short)z8[j]);
                float g = y * z * __builtin_amdgcn_rcpf(1.f + __expf(-z));
                ssl += g * g;
                float nw = (j < 4) ? nw0[j] : nw1[j - 4];
                a8[j] = __builtin_bit_cast(short, (__bf16)(g * nw));
            }
            if (issue == 0) ssA += ssl; else ssB += ssl;
            const int phys = (row << 7) | (colb ^ ((row & 7) << 4));
            *(s16x8*)(lds + phys) = a8;
        }
        asm volatile("s_waitcnt vmcnt(0) lgkmcnt(0)" ::: "memory");
        __builtin_amdgcn_s_barrier();
        bf16x8 a[4][2];
#pragma unroll
        for (int fm = 0; fm < 4; fm++)
#pragma unroll
            for (int ks = 0; ks < 2; ks++)
                a[fm][ks] = rdfrag(lds, 0, wm * 64 + fm * 16 + lrow, ks, lane);
        __builtin_amdgcn_s_setprio(1);
#pragma unroll
        for (int fn = 0; fn < 2; fn++) {
            bf16x8 b0 = rdfrag(lds, 16384, wn * 32 + fn * 16 + lrow, 0, lane);
            bf16x8 b1 = rdfrag(lds, 16384, wn * 32 + fn * 16 + lrow, 1, lane);
#pragma unroll
            for (int fm = 0; fm < 4; fm++) {
                acc[fm][fn] = __builtin_amdgcn_mfma_f32_16x16x32_bf16(a[fm][0], b0, acc[fm][fn], 0, 0, 0);
                acc[fm][fn] = __builtin_amdgcn_mfma_f32_16x16x32_bf16(a[fm][1], b1, acc[fm][fn], 0, 0, 0);
            }
        }
        __builtin_amdgcn_s_setprio(0);
        __builtin_amdgcn_s_barrier();
    }

    // per-row rms: reduce 8 staging threads' partials (consecutive lanes)
#pragma unroll
    for (int off = 1; off < 8; off <<= 1) {
        ssA += __shfl_xor(ssA, off);
        ssB += __shfl_xor(ssB, off);
    }
    float* rmsh = (float*)(lds + 32768);
    if ((tid & 7) == 0) {
        rmsh[rA]      = rsqrtf(ssA * (1.f / (float)DI) + 1e-5f);
        rmsh[64 + rA] = rsqrtf(ssB * (1.f / (float)DI) + 1e-5f);
    }
    __syncthreads();

    const int gm_base = m0 + wm * 64 + ((lane >> 4) << 2);
    const int gn_base = n0 + wn * 32 + (lane & 15);
#pragma unroll
    for (int fm = 0; fm < 4; fm++) {
        const int gmb = gm_base + fm * 16;
#pragma unroll
        for (int fn = 0; fn < 2; fn++) {
            const int gn = gn_base + fn * 16;
#pragma unroll
            for (int r = 0; r < 4; r++) {
                float rms = rmsh[gmb + r - m0];
                out[(size_t)(gmb + r) * DM + gn] = acc[fm][fn][r] * rms;
            }
        }
    }
}

// ---------------- depthwise causal conv + SiLU (register row-reuse) ----------------
__global__ __launch_bounds__(256) void k_conv(const __bf16* __restrict__ xbcraw, const float* __restrict__ conv_w,
                                              const float* __restrict__ conv_b, __bf16* __restrict__ xconv) {
    __shared__ float wsh[256 * 4];
    __shared__ float bsh[256];
    const int tid  = threadIdx.x;
    const int gsub = tid & 31;
    const int roct = tid >> 5;
    const int ch_base_blk = blockIdx.x * 256;
    *(f32x4*)&wsh[tid * 4] = *(const f32x4*)&conv_w[ch_base_blk * 4 + tid * 4];
    bsh[tid] = conv_b[ch_base_blk + tid];
    __syncthreads();

    const int ch0  = ch_base_blk + gsub * 8;
    const int row0 = (blockIdx.y * 8 + roct) * 8;
    const int l0   = row0 & (L_ - 1);
    const __bf16* src = xbcraw + (size_t)row0 * CD + ch0;

    s16x8 rr[11];
#pragma unroll
    for (int j = 0; j < 11; j++) {
        int ll = l0 - 3 + j;
        if (ll >= 0) rr[j] = *(const s16x8*)(src + (size_t)(j - 3) * CD);
        else         rr[j] = (s16x8){0, 0, 0, 0, 0, 0, 0, 0};
    }

    const int chl = gsub * 8;
    float w[8][4], bias[8];
#pragma unroll
    for (int j = 0; j < 8; j++) {
        bias[j] = bsh[chl + j];
#pragma unroll
        for (int k = 0; k < 4; k++) w[j][k] = wsh[(chl + j) * 4 + k];
    }

    __bf16* dst = xconv + (size_t)row0 * CD + ch0;
#pragma unroll
    for (int orow = 0; orow < 8; orow++) {
        float a[8];
#pragma unroll
        for (int j = 0; j < 8; j++) a[j] = bias[j];
#pragma unroll
        for (int k = 0; k < 4; k++) {
            s16x8 v = rr[orow + k];
#pragma unroll
            for (int j = 0; j < 8; j++)
                a[j] += w[j][k] * (float)__builtin_bit_cast(__bf16, (short)v[j]);
        }
        s16x8 o;
#pragma unroll
        for (int j = 0; j < 8; j++)
            o[j] = __builtin_bit_cast(short, (__bf16)(a[j] * __builtin_amdgcn_rcpf(1.f + __expf(-a[j]))));
        *(s16x8*)(dst + (size_t)orow * CD) = o;
    }
}

// ---------------- CBT via MFMA: cbt[b][c][i][j] = sum_n C[i][n]*B[j][n] ----------------
__global__ __launch_bounds__(256) void k_cbt(const __bf16* __restrict__ xconv, float* __restrict__ cbt) {
    const int c = blockIdx.x, b = blockIdx.y;
    const int tid = threadIdx.x, wv = tid >> 6, lane = tid & 63;
    const int lrow = lane & 15, lko = (lane >> 4) * 8;
    __shared__ __align__(16) __bf16 Csh[64 * 136];
    __shared__ __align__(16) __bf16 Bsh[64 * 136];
    const size_t rowbase = (size_t)b * L_ + c * CHUNK;
#pragma unroll
    for (int q = 0; q < 32; q++) {
        int i = q * 2 + (wv >> 1);
        int n = (wv & 1) * 64 + lane;
        const __bf16* base = xconv + (rowbase + i) * CD + DI;
        Bsh[i * 136 + n] = base[n];
        Csh[i * 136 + n] = base[DS + n];
    }
    __syncthreads();
    f32x4 acc[4];
    f32x4 z4 = {0.f, 0.f, 0.f, 0.f};
#pragma unroll
    for (int jt = 0; jt < 4; jt++) acc[jt] = z4;
#pragma unroll
    for (int ks = 0; ks < 4; ks++) {
        bf16x8 a = *(const bf16x8*)&Csh[(wv * 16 + lrow) * 136 + ks * 32 + lko];
#pragma unroll
        for (int jt = 0; jt < 4; jt++) {
            bf16x8 bb = *(const bf16x8*)&Bsh[(jt * 16 + lrow) * 136 + ks * 32 + lko];
            acc[jt] = __builtin_amdgcn_mfma_f32_16x16x32_bf16(a, bb, acc[jt], 0, 0, 0);
        }
    }
    float* o = cbt + (size_t)(b * NC + c) * 4096;
#pragma unroll
    for (int jt = 0; jt < 4; jt++)
#pragma unroll
        for (int r = 0; r < 4; r++) {
            int i = wv * 16 + (lane >> 4) * 4 + r;
            int j = jt * 16 + lrow;
            o[i * 64 + j] = acc[jt][r];
        }
}

// ---------------- SSD part A (MFMA): chunk states only ----------------
__global__ __launch_bounds__(256) void k_ssd_a(const __bf16* __restrict__ xconv, const float* __restrict__ dtbuf,
                                               const float* __restrict__ A_log,
                                               __bf16* __restrict__ states, float* __restrict__ asum) {
    const int h = blockIdx.x, c = blockIdx.y, b = blockIdx.z;
    const int tid = threadIdx.x, wv = tid >> 6, lane = tid & 63;
    const int lrow = lane & 15, lko = (lane >> 4) * 8;
    __shared__ __align__(16) __bf16 xT[64 * 72];
    __shared__ __align__(16) __bf16 xsc[64 * 72];
    __shared__ __align__(16) __bf16 BT[128 * 72];
    __shared__ float dts[64], cum[64];

    const float Ah = -__expf(A_log[h]);
    const size_t rowbase = (size_t)b * L_ + c * CHUNK;

    float dtv = 0.f;
    if (wv == 0) { dtv = dtbuf[(rowbase + lane) * NH + h]; dts[lane] = dtv; }
#pragma unroll
    for (int q = 0; q < 16; q++) {
        int i = q * 4 + wv;
        xT[lane * 72 + i] = xconv[(rowbase + i) * CD + h * HD + lane];
    }
#pragma unroll
    for (int q = 0; q < 32; q++) {
        int i = q * 2 + (wv >> 1);
        int n = (wv & 1) * 64 + lane;
        BT[n * 72 + i] = xconv[(rowbase + i) * CD + DI + n];
    }
    if (wv == 0) {
        float v = Ah * dtv;
#pragma unroll
        for (int o = 1; o < 64; o <<= 1) { float t = __shfl_up(v, o); if (lane >= o) v += t; }
        cum[lane] = v;
        if (lane == 63) asum[(b * NC + c) * NH + h] = v;
    }
    __syncthreads();

    const float cum63 = cum[63];
#pragma unroll
    for (int q = 0; q < 16; q++) {
        int i = q * 4 + wv;
        float dcfi = __expf(cum63 - cum[i]) * dts[i];
        xsc[lane * 72 + i] = (__bf16)((float)xT[lane * 72 + i] * dcfi);
    }
    __syncthreads();

    f32x4 z4 = {0.f, 0.f, 0.f, 0.f};
    f32x4 accS[8];
#pragma unroll
    for (int nt = 0; nt < 8; nt++) accS[nt] = z4;
#pragma unroll
    for (int ks = 0; ks < 2; ks++) {
        bf16x8 a = *(const bf16x8*)&xsc[(wv * 16 + lrow) * 72 + ks * 32 + lko];
#pragma unroll
        for (int nt = 0; nt < 8; nt++) {
            bf16x8 bb = *(const bf16x8*)&BT[(nt * 16 + lrow) * 72 + ks * 32 + lko];
            accS[nt] = __builtin_amdgcn_mfma_f32_16x16x32_bf16(a, bb, accS[nt], 0, 0, 0);
        }
    }
    __bf16* sp = states + ((size_t)(b * NC + c) * NH + h) * 8192;
#pragma unroll
    for (int nt = 0; nt < 8; nt++)
#pragma unroll
        for (int r = 0; r < 4; r++) {
            int p = wv * 16 + (lane >> 4) * 4 + r;
            int n = nt * 16 + lrow;
            sp[p * 128 + n] = (__bf16)accS[nt][r];
        }
}

// ---------------- inter-chunk scan (4-deep load prefetch, in-place) ----------------
__global__ __launch_bounds__(256) void k_scan(__bf16* __restrict__ states, const float* __restrict__ asum) {
    const int seg = blockIdx.x, h = blockIdx.y, b = blockIdx.z;
    __shared__ float efs[NC];
    if (threadIdx.x < NC) efs[threadIdx.x] = __expf(asum[(b * NC + threadIdx.x) * NH + h]);
    __syncthreads();
    const int e0 = seg * 1024 + threadIdx.x * 4;
    __bf16* base = states + ((size_t)(b * NC) * NH + h) * 8192 + e0;
    const size_t cs = (size_t)NH * 8192;
    float S[4] = {0.f, 0.f, 0.f, 0.f};
    s16x4 r0 = *(const s16x4*)(base);
    s16x4 r1 = *(const s16x4*)(base + cs);
    s16x4 r2 = *(const s16x4*)(base + 2 * cs);
    s16x4 r3;
#define SCAN_STEP(RV, CC)                                                                  \
    {                                                                                      \
        s16x4 o; float e = efs[CC];                                                        \
        _Pragma("unroll")                                                                  \
        for (int q = 0; q < 4; q++) {                                                      \
            float t = (float)__builtin_bit_cast(__bf16, (short)RV[q]);                     \
            o[q] = __builtin_bit_cast(short, (__bf16)S[q]);                                \
            S[q] = e * S[q] + t;                                                           \
        }                                                                                  \
        *(s16x4*)(base + (size_t)(CC) * cs) = o;                                           \
    }
    for (int c = 0; c < NC; c += 4) {
        r3 = *(const s16x4*)(base + (size_t)(c + 3) * cs);
        SCAN_STEP(r0, c);
        if (c + 4 < NC) r0 = *(const s16x4*)(base + (size_t)(c + 4) * cs);
        SCAN_STEP(r1, c + 1);
        if (c + 5 < NC) r1 = *(const s16x4*)(base + (size_t)(c + 5) * cs);
        SCAN_STEP(r2, c + 2);
        if (c + 6 < NC) r2 = *(const s16x4*)(base + (size_t)(c + 6) * cs);
        SCAN_STEP(r3, c + 3);
    }
#undef SCAN_STEP
}

// ---------------- SSD part B (MFMA, merged): Y = (M+D·I)@x + exp(cum)*(C@Sprev^T) ----------------
__global__ __launch_bounds__(256) void k_ssd_b(const __bf16* __restrict__ xconv, const float* __restrict__ dtbuf,
                                               const __bf16* __restrict__ states, const float* __restrict__ A_log,
                                               const float* __restrict__ cbt, const float* __restrict__ D_param,
                                               __bf16* __restrict__ ybuf) {
    const int h = blockIdx.x, c = blockIdx.y, b = blockIdx.z;
    const int tid = threadIdx.x, wv = tid >> 6, lane = tid & 63;
    const int lrow = lane & 15, lko = (lane >> 4) * 8;
    __shared__ __align__(16) __bf16 xT[64 * 72];
    __shared__ __align__(16) __bf16 Ms[64 * 72];
    __shared__ __align__(16) __bf16 Csh[64 * 136];
    __shared__ __align__(16) __bf16 Sps[64 * 136];
    __shared__ float dts[64], cum[64];

    const float Ah = -__expf(A_log[h]);
    const size_t rowbase = (size_t)b * L_ + c * CHUNK;
    const __bf16* sp = states + ((size_t)(b * NC + c) * NH + h) * 8192;
#pragma unroll
    for (int q = 0; q < 32; q++) {
        int i = q * 2 + (wv >> 1);
        int n = (wv & 1) * 64 + lane;
        Csh[i * 136 + n] = xconv[(rowbase + i) * CD + DI + DS + n];
        Sps[i * 136 + n] = sp[i * 128 + n];
    }
#pragma unroll
    for (int q = 0; q < 16; q++) {
        int i = q * 4 + wv;
        xT[lane * 72 + i] = xconv[(rowbase + i) * CD + h * HD + lane];
    }
    if (wv == 0) {
        float dtv = dtbuf[(rowbase + lane) * NH + h];
        dts[lane] = dtv;
        float v = Ah * dtv;
#pragma unroll
        for (int o = 1; o < 64; o <<= 1) { float t = __shfl_up(v, o); if (lane >= o) v += t; }
        cum[lane] = v;
    }
    __syncthreads();

    const float Dh = D_param[h];
    const float* cbt_bc = cbt + (size_t)(b * NC + c) * 4096;
#pragma unroll
    for (int q = 0; q < 16; q++) {
        int i = q * 4 + wv, j = lane;
        float m = 0.f;
        if (j <= i) m = cbt_bc[i * 64 + j] * __expf(cum[i] - cum[j]) * dts[j];
        if (j == i) m += Dh;
        Ms[i * 72 + j] = (__bf16)m;
    }
    __syncthreads();

    f32x4 z4 = {0.f, 0.f, 0.f, 0.f};
    f32x4 accY[4], accO[4];
#pragma unroll
    for (int pt = 0; pt < 4; pt++) { accY[pt] = z4; accO[pt] = z4; }
#pragma unroll
    for (int ks = 0; ks < 2; ks++) {
        bf16x8 a = *(const bf16x8*)&Ms[(wv * 16 + lrow) * 72 + ks * 32 + lko];
#pragma unroll
        for (int pt = 0; pt < 4; pt++) {
            bf16x8 bb = *(const bf16x8*)&xT[(pt * 16 + lrow) * 72 + ks * 32 + lko];
            accY[pt] = __builtin_amdgcn_mfma_f32_16x16x32_bf16(a, bb, accY[pt], 0, 0, 0);
        }
    }
#pragma unroll
    for (int ks = 0; ks < 4; ks++) {
        bf16x8 a = *(const bf16x8*)&Csh[(wv * 16 + lrow) * 136 + ks * 32 + lko];
#pragma unroll
        for (int pt = 0; pt < 4; pt++) {
            bf16x8 bb = *(const bf16x8*)&Sps[(pt * 16 + lrow) * 136 + ks * 32 + lko];
            accO[pt] = __builtin_amdgcn_mfma_f32_16x16x32_bf16(a, bb, accO[pt], 0, 0, 0);
        }
    }
#pragma unroll
    for (int r = 0; r < 4; r++) {
        int i = wv * 16 + (lane >> 4) * 4 + r;
        float ef = __expf(cum[i]);
#pragma unroll
        for (int pt = 0; pt < 4; pt++) {
            size_t idx = (rowbase + i) * DI + h * HD + pt * 16 + lrow;
            ybuf[idx] = (__bf16)(accY[pt][r] + ef * accO[pt][r]);
        }
    }
}

// ---------------- gate (silu(z)) + RMSNorm -> bf16 (fallback path) ----------------
__global__ __launch_bounds__(256) void k_gate_norm(const __bf16* __restrict__ ybuf, const __bf16* __restrict__ zbuf,
                                                   const float* __restrict__ norm_w, __bf16* __restrict__ ybf) {
    const int r = blockIdx.x;
    const int tid = threadIdx.x;
    const int col0 = tid * 8;
    s16x8 y8 = *(const s16x8*)(ybuf + (size_t)r * DI + col0);
    s16x8 z8 = *(const s16x8*)(zbuf + (size_t)r * DI + col0);
    float v[8];
    float ss = 0.f;
#pragma unroll
    for (int q = 0; q < 8; q++) {
        float y = (float)__builtin_bit_cast(__bf16, (short)y8[q]);
        float z = (float)__builtin_bit_cast(__bf16, (short)z8[q]);
        float g = z * __builtin_amdgcn_rcpf(1.f + __expf(-z));
        v[q] = y * g;
        ss += v[q] * v[q];
    }
#pragma unroll
    for (int o = 32; o > 0; o >>= 1) ss += __shfl_down(ss, o);
    __shared__ float wsum[4];
    __shared__ float rmss;
    if ((tid & 63) == 0) wsum[tid >> 6] = ss;
    __syncthreads();
    if (tid == 0) {
        float t = wsum[0] + wsum[1] + wsum[2] + wsum[3];
        rmss = rsqrtf(t / (float)DI + 1e-5f);
    }
    __syncthreads();
    float rm = rmss;
    s16x8 o8;
#pragma unroll
    for (int q = 0; q < 8; q++)
        o8[q] = __builtin_bit_cast(short, (__bf16)(v[q] * rm * norm_w[col0 + q]));
    *(s16x8*)(ybf + (size_t)r * DI + col0) = o8;
}

// ---------------- launcher ----------------
extern "C" void kernel_launch(void* const* d_in, const int* in_sizes, int n_in,
                              void* d_out, int out_size, void* d_ws, size_t ws_size,
                              hipStream_t stream) {
    const float* u       = (const float*)d_in[0];
    const float* W_in    = (const float*)d_in[1];
    const float* conv_w  = (const float*)d_in[2];
    const float* conv_b  = (const float*)d_in[3];
    const float* dt_bias = (const float*)d_in[4];
    const float* A_log   = (const float*)d_in[5];
    const float* D_param = (const float*)d_in[6];
    const float* norm_w  = (const float*)d_in[7];
    const float* W_out   = (const float*)d_in[8];
    float* out = (float*)d_out;

    // ---- static workspace plan ----
    constexpr size_t OFF_WOBF  = 0;
    constexpr size_t OFF_ZBUF  = 4194304;
    constexpr size_t OFF_DT    = 37748736;
    constexpr size_t OFF_ASUM  = 38797312;
    constexpr size_t OFF_XCONV = 38813696;
    constexpr size_t OFF_CBT   = 76562432;
    constexpr size_t OFF_BIG   = 78659584;
    constexpr size_t NEED      = 145768448;   // base plan
    constexpr size_t OFF_YB2   = 145768448;   // fused-path ybuf (33.5 MB)
    constexpr size_t NEED2     = 179322880;
    if (ws_size < NEED) return;
    const bool fused = (ws_size >= NEED2);    // deterministic per harness

    char* ws = (char*)d_ws;
    __bf16* wobf   = (__bf16*)(ws + OFF_WOBF);
    __bf16* zbuf   = (__bf16*)(ws + OFF_ZBUF);
    float*  dtbuf  = (float*) (ws + OFF_DT);
    float*  asum   = (float*) (ws + OFF_ASUM);
    __bf16* xconv  = (__bf16*)(ws + OFF_XCONV);
    float*  cbt    = (float*) (ws + OFF_CBT);
    __bf16* ubf    = (__bf16*)(ws + OFF_BIG);
    __bf16* wibf   = (__bf16*)(ws + OFF_BIG + 16777216);
    __bf16* xbcraw = (__bf16*)(ws + OFF_BIG + 16777216 + 9437184);
    __bf16* states = (__bf16*)(ws + OFF_BIG);            // reuses ubf/wibf/xbcraw after conv
    __bf16* ybf    = (__bf16*)(ws + OFF_XCONV);          // fallback: reuses xconv after ssd_b
    __bf16* ybuf   = fused ? (__bf16*)(ws + OFF_YB2)     // fused: dedicated (out aliases d_out)
                           : (__bf16*)d_out;

    (void)hipFuncSetAttribute((const void*)k_gemm1,  hipFuncAttributeMaxDynamicSharedMemorySize, 32768);
    (void)hipFuncSetAttribute((const void*)k_gemm2,  hipFuncAttributeMaxDynamicSharedMemorySize, 32768);
    (void)hipFuncSetAttribute((const void*)k_gemm2f, hipFuncAttributeMaxDynamicSharedMemorySize, 33280);

    constexpr int QTOT = ROWS * DM / 4 + NPAD2 * DM / 4 + DM * DI / 4;
    k_convert_all<<<(QTOT + 255) / 256, 256, 0, stream>>>(u, W_in, W_out, ubf, wibf, wobf);

    k_gemm1<<<2240, 512, 32768, stream>>>(ubf, wibf, zbuf, xbcraw, dtbuf, dt_bias);
    k_conv<<<dim3(9, 128), 256, 0, stream>>>(xbcraw, conv_w, conv_b, xconv);
    k_cbt<<<dim3(NC, B_), 256, 0, stream>>>(xconv, cbt);
    k_ssd_a<<<dim3(NH, NC, B_), 256, 0, stream>>>(xconv, dtbuf, A_log, states, asum);
    k_scan<<<dim3(8, NH, B_), 256, 0, stream>>>(states, asum);
    k_ssd_b<<<dim3(NH, NC, B_), 256, 0, stream>>>(xconv, dtbuf, states, A_log, cbt, D_param, ybuf);
    if (fused) {
        k_gemm2f<<<512, 512, 33280, stream>>>(ybuf, zbuf, norm_w, wobf, out);
    } else {
        k_gate_norm<<<ROWS, 256, 0, stream>>>(ybuf, zbuf, norm_w, ybf);
        k_gemm2<<<512, 512, 32768, stream>>>(ybf, wobf, out);
    }
}

// Round 17
// 299.568 us; speedup vs baseline: 1.1029x; 1.1029x over previous
//
#include <hip/hip_runtime.h>
#include <hip/hip_bf16.h>
#include <math.h>

#define B_    2
#define L_    4096
#define DM    1024
#define DI    2048
#define DS    128
#define NH    32
#define HD    64
#define CHUNK 64
#define NC    (L_/CHUNK)          // 64
#define CD    (DI + 2*DS)         // 2304
#define ROWS  (B_*L_)             // 8192
#define NOUT  (2*DI + 2*DS + NH)  // 4384
#define NPAD2 4608                // conversion pad (wibf rows; tiles use 35*128=4480)

typedef __attribute__((ext_vector_type(4))) float f32x4;
typedef __attribute__((ext_vector_type(8))) __bf16 bf16x8;
typedef __attribute__((ext_vector_type(4))) short s16x4;
typedef __attribute__((ext_vector_type(8))) short s16x8;

// ---------------- fused conversion kernel (u, W_in(pad), W_out) ----------------
__global__ __launch_bounds__(256) void k_convert_all(const float* __restrict__ u, const float* __restrict__ W_in,
                                                     const float* __restrict__ W_out, __bf16* __restrict__ ubf,
                                                     __bf16* __restrict__ wibf, __bf16* __restrict__ wobf) {
    int i = blockIdx.x * 256 + threadIdx.x;
    const int QU  = ROWS * DM / 4;
    const int QWI = NPAD2 * DM / 4;
    const int QWO = DM * DI / 4;
    const float* s = nullptr;
    __bf16* d;
    bool zero = false;
    if (i < QU) {
        s = u + (size_t)i * 4; d = ubf + (size_t)i * 4;
    } else if (i < QU + QWI) {
        int j = i - QU;
        d = wibf + (size_t)j * 4;
        if (j < NOUT * DM / 4) s = W_in + (size_t)j * 4; else zero = true;
    } else if (i < QU + QWI + QWO) {
        int j = i - QU - QWI;
        s = W_out + (size_t)j * 4; d = wobf + (size_t)j * 4;
    } else return;
    s16x4 o = {0, 0, 0, 0};
    if (!zero) {
        f32x4 v = *(const f32x4*)s;
#pragma unroll
        for (int q = 0; q < 4; q++) o[q] = __builtin_bit_cast(short, (__bf16)v[q]);
    }
    *(s16x4*)d = o;
}

// ---------------- staging / frag-read helpers (T2 swizzle, proven 0-conflict) ----------------
__device__ __forceinline__ void stage_half(const __bf16* __restrict__ G, int ldg, int grow0, int kt,
                                           char* lds, int ldsoff, int tid, int wave) {
#pragma unroll
    for (int issue = 0; issue < 2; issue++) {
        int o   = issue * 8192 + tid * 16;
        int row = o >> 7;
        int cb  = (o & 127) ^ ((row & 7) << 4);
        const __bf16* src = G + (size_t)(grow0 + row) * ldg + kt + (cb >> 1);
        char* ldsbase = lds + ldsoff + issue * 8192 + wave * 1024;
        __builtin_amdgcn_global_load_lds((const __attribute__((address_space(1))) void*)src,
                                         (__attribute__((address_space(3))) void*)ldsbase,
                                         16, 0, 0);
    }
}

__device__ __forceinline__ bf16x8 rdfrag(const char* lds, int ldsoff, int r, int ks, int lane) {
    int logical = r * 128 + ks * 64 + ((lane >> 4) << 4);
    int phys    = logical ^ ((r & 7) << 4);
    return *(const bf16x8*)(lds + ldsoff + phys);
}

// =====================================================================
// 128x128 GEMM core, BK=64, 8 waves (2m x 4n, wave tile 64x32),
// SINGLE-buffered 32 KiB LDS -> 4 blocks/CU (m97/m114 cross-block
// mechanism). launch_bounds min-waves must stay 4 — higher spills (r12).
// =====================================================================
__device__ __forceinline__ void gemm128x128_core(const __bf16* __restrict__ Ag, const __bf16* __restrict__ Bg,
                                                 int K, int m0, int n0, char* lds, f32x4 acc[4][2]) {
    const int tid = threadIdx.x, wave = tid >> 6, lane = tid & 63;
    const int wm = wave >> 2, wn = wave & 3, lrow = lane & 15;
    const int KT = K >> 6;

    for (int t = 0; t < KT; t++) {
        const int kt = t << 6;
        stage_half(Ag, K, m0, kt, lds, 0,     tid, wave);
        stage_half(Bg, K, n0, kt, lds, 16384, tid, wave);
        asm volatile("s_waitcnt vmcnt(0)" ::: "memory");
        __builtin_amdgcn_s_barrier();
        bf16x8 a[4][2];
#pragma unroll
        for (int fm = 0; fm < 4; fm++)
#pragma unroll
            for (int ks = 0; ks < 2; ks++)
                a[fm][ks] = rdfrag(lds, 0, wm * 64 + fm * 16 + lrow, ks, lane);
        __builtin_amdgcn_s_setprio(1);
#pragma unroll
        for (int fn = 0; fn < 2; fn++) {
            bf16x8 b0 = rdfrag(lds, 16384, wn * 32 + fn * 16 + lrow, 0, lane);
            bf16x8 b1 = rdfrag(lds, 16384, wn * 32 + fn * 16 + lrow, 1, lane);
#pragma unroll
            for (int fm = 0; fm < 4; fm++) {
                acc[fm][fn] = __builtin_amdgcn_mfma_f32_16x16x32_bf16(a[fm][0], b0, acc[fm][fn], 0, 0, 0);
                acc[fm][fn] = __builtin_amdgcn_mfma_f32_16x16x32_bf16(a[fm][1], b1, acc[fm][fn], 0, 0, 0);
            }
        }
        __builtin_amdgcn_s_setprio(0);
        __builtin_amdgcn_s_barrier();
    }
}

// GEMM1: zxbcdt = u @ W_in^T, fused split + softplus epilogue.
__global__ __launch_bounds__(512, 4) void k_gemm1(const __bf16* __restrict__ ubf, const __bf16* __restrict__ wibf,
                                                  __bf16* __restrict__ zbuf, __bf16* __restrict__ xbcraw,
                                                  float* __restrict__ dtbuf, const float* __restrict__ dt_bias) {
    extern __shared__ char lds[];
    f32x4 acc[4][2];
    f32x4 z4 = {0.f, 0.f, 0.f, 0.f};
#pragma unroll
    for (int i = 0; i < 4; i++)
#pragma unroll
        for (int j = 0; j < 2; j++) acc[i][j] = z4;

    int bid = blockIdx.x;
    int wg  = (bid & 7) * 280 + (bid >> 3);    // 2240 wgs, bijective
    int m0  = (wg / 35) * 128;
    int n0  = (wg % 35) * 128;
    gemm128x128_core(ubf, wibf, DM, m0, n0, lds, acc);

    const int lane = threadIdx.x & 63, wave = threadIdx.x >> 6;
    const int wm = wave >> 2, wn = wave & 3;
    const int gm_base = m0 + wm * 64 + ((lane >> 4) << 2);
    const int gn_base = n0 + wn * 32 + (lane & 15);
#pragma unroll
    for (int fm = 0; fm < 4; fm++) {
        const int gmb = gm_base + fm * 16;
#pragma unroll
        for (int fn = 0; fn < 2; fn++) {
            const int gn = gn_base + fn * 16;
            if (gn < DI) {
#pragma unroll
                for (int r = 0; r < 4; r++)
                    zbuf[(size_t)(gmb + r) * DI + gn] = (__bf16)acc[fm][fn][r];
            } else if (gn < DI + CD) {
#pragma unroll
                for (int r = 0; r < 4; r++)
                    xbcraw[(size_t)(gmb + r) * CD + (gn - DI)] = (__bf16)acc[fm][fn][r];
            } else if (gn < NOUT) {
                const int hh = gn - (DI + CD);
                const float bb = dt_bias[hh];
#pragma unroll
                for (int r = 0; r < 4; r++) {
                    float x = acc[fm][fn][r] + bb;
                    float sp = (x > 20.f) ? x : log1pf(__expf(x));
                    dtbuf[(size_t)(gmb + r) * NH + hh] = sp;
                }
            }
        }
    }
}

// GEMM2: out = ynorm @ W_out^T  (128x128 tiles, grid 512)
__global__ __launch_bounds__(512, 4) void k_gemm2(const __bf16* __restrict__ ybf, const __bf16* __restrict__ wobf,
                                                  float* __restrict__ out) {
    extern __shared__ char lds[];
    f32x4 acc[4][2];
    f32x4 z4 = {0.f, 0.f, 0.f, 0.f};
#pragma unroll
    for (int i = 0; i < 4; i++)
#pragma unroll
        for (int j = 0; j < 2; j++) acc[i][j] = z4;

    int bid = blockIdx.x;
    int wg  = (bid & 7) * 64 + (bid >> 3);     // 512 wgs, bijective
    int m0  = (wg / 8) * 128;
    int n0  = (wg % 8) * 128;
    gemm128x128_core(ybf, wobf, DI, m0, n0, lds, acc);

    const int lane = threadIdx.x & 63, wave = threadIdx.x >> 6;
    const int wm = wave >> 2, wn = wave & 3;
    const int gm_base = m0 + wm * 64 + ((lane >> 4) << 2);
    const int gn_base = n0 + wn * 32 + (lane & 15);
#pragma unroll
    for (int fm = 0; fm < 4; fm++) {
        const int gmb = gm_base + fm * 16;
#pragma unroll
        for (int fn = 0; fn < 2; fn++) {
            const int gn = gn_base + fn * 16;
#pragma unroll
            for (int r = 0; r < 4; r++)
                out[(size_t)(gmb + r) * DM + gn] = acc[fm][fn][r];
        }
    }
}

// ---------------- depthwise causal conv + SiLU (register row-reuse) ----------------
__global__ __launch_bounds__(256) void k_conv(const __bf16* __restrict__ xbcraw, const float* __restrict__ conv_w,
                                              const float* __restrict__ conv_b, __bf16* __restrict__ xconv) {
    __shared__ float wsh[256 * 4];
    __shared__ float bsh[256];
    const int tid  = threadIdx.x;
    const int gsub = tid & 31;
    const int roct = tid >> 5;
    const int ch_base_blk = blockIdx.x * 256;
    *(f32x4*)&wsh[tid * 4] = *(const f32x4*)&conv_w[ch_base_blk * 4 + tid * 4];
    bsh[tid] = conv_b[ch_base_blk + tid];
    __syncthreads();

    const int ch0  = ch_base_blk + gsub * 8;
    const int row0 = (blockIdx.y * 8 + roct) * 8;
    const int l0   = row0 & (L_ - 1);
    const __bf16* src = xbcraw + (size_t)row0 * CD + ch0;

    s16x8 rr[11];
#pragma unroll
    for (int j = 0; j < 11; j++) {
        int ll = l0 - 3 + j;
        if (ll >= 0) rr[j] = *(const s16x8*)(src + (size_t)(j - 3) * CD);
        else         rr[j] = (s16x8){0, 0, 0, 0, 0, 0, 0, 0};
    }

    const int chl = gsub * 8;
    float w[8][4], bias[8];
#pragma unroll
    for (int j = 0; j < 8; j++) {
        bias[j] = bsh[chl + j];
#pragma unroll
        for (int k = 0; k < 4; k++) w[j][k] = wsh[(chl + j) * 4 + k];
    }

    __bf16* dst = xconv + (size_t)row0 * CD + ch0;
#pragma unroll
    for (int orow = 0; orow < 8; orow++) {
        float a[8];
#pragma unroll
        for (int j = 0; j < 8; j++) a[j] = bias[j];
#pragma unroll
        for (int k = 0; k < 4; k++) {
            s16x8 v = rr[orow + k];
#pragma unroll
            for (int j = 0; j < 8; j++)
                a[j] += w[j][k] * (float)__builtin_bit_cast(__bf16, (short)v[j]);
        }
        s16x8 o;
#pragma unroll
        for (int j = 0; j < 8; j++)
            o[j] = __builtin_bit_cast(short, (__bf16)(a[j] * __builtin_amdgcn_rcpf(1.f + __expf(-a[j]))));
        *(s16x8*)(dst + (size_t)orow * CD) = o;
    }
}

// ---------------- CBT via MFMA: cbt[b][c][i][j] = sum_n C[i][n]*B[j][n] ----------------
__global__ __launch_bounds__(256) void k_cbt(const __bf16* __restrict__ xconv, float* __restrict__ cbt) {
    const int c = blockIdx.x, b = blockIdx.y;
    const int tid = threadIdx.x, wv = tid >> 6, lane = tid & 63;
    const int lrow = lane & 15, lko = (lane >> 4) * 8;
    __shared__ __align__(16) __bf16 Csh[64 * 136];
    __shared__ __align__(16) __bf16 Bsh[64 * 136];
    const size_t rowbase = (size_t)b * L_ + c * CHUNK;
#pragma unroll
    for (int q = 0; q < 32; q++) {
        int i = q * 2 + (wv >> 1);
        int n = (wv & 1) * 64 + lane;
        const __bf16* base = xconv + (rowbase + i) * CD + DI;
        Bsh[i * 136 + n] = base[n];
        Csh[i * 136 + n] = base[DS + n];
    }
    __syncthreads();
    f32x4 acc[4];
    f32x4 z4 = {0.f, 0.f, 0.f, 0.f};
#pragma unroll
    for (int jt = 0; jt < 4; jt++) acc[jt] = z4;
#pragma unroll
    for (int ks = 0; ks < 4; ks++) {
        bf16x8 a = *(const bf16x8*)&Csh[(wv * 16 + lrow) * 136 + ks * 32 + lko];
#pragma unroll
        for (int jt = 0; jt < 4; jt++) {
            bf16x8 bb = *(const bf16x8*)&Bsh[(jt * 16 + lrow) * 136 + ks * 32 + lko];
            acc[jt] = __builtin_amdgcn_mfma_f32_16x16x32_bf16(a, bb, acc[jt], 0, 0, 0);
        }
    }
    float* o = cbt + (size_t)(b * NC + c) * 4096;
#pragma unroll
    for (int jt = 0; jt < 4; jt++)
#pragma unroll
        for (int r = 0; r < 4; r++) {
            int i = wv * 16 + (lane >> 4) * 4 + r;
            int j = jt * 16 + lrow;
            o[i * 64 + j] = acc[jt][r];
        }
}

// ---------------- SSD part A (MFMA): chunk states only ----------------
__global__ __launch_bounds__(256) void k_ssd_a(const __bf16* __restrict__ xconv, const float* __restrict__ dtbuf,
                                               const float* __restrict__ A_log,
                                               __bf16* __restrict__ states, float* __restrict__ asum) {
    const int h = blockIdx.x, c = blockIdx.y, b = blockIdx.z;
    const int tid = threadIdx.x, wv = tid >> 6, lane = tid & 63;
    const int lrow = lane & 15, lko = (lane >> 4) * 8;
    __shared__ __align__(16) __bf16 xT[64 * 72];
    __shared__ __align__(16) __bf16 xsc[64 * 72];
    __shared__ __align__(16) __bf16 BT[128 * 72];
    __shared__ float dts[64], cum[64];

    const float Ah = -__expf(A_log[h]);
    const size_t rowbase = (size_t)b * L_ + c * CHUNK;

    float dtv = 0.f;
    if (wv == 0) { dtv = dtbuf[(rowbase + lane) * NH + h]; dts[lane] = dtv; }
#pragma unroll
    for (int q = 0; q < 16; q++) {
        int i = q * 4 + wv;
        xT[lane * 72 + i] = xconv[(rowbase + i) * CD + h * HD + lane];
    }
#pragma unroll
    for (int q = 0; q < 32; q++) {
        int i = q * 2 + (wv >> 1);
        int n = (wv & 1) * 64 + lane;
        BT[n * 72 + i] = xconv[(rowbase + i) * CD + DI + n];
    }
    if (wv == 0) {
        float v = Ah * dtv;
#pragma unroll
        for (int o = 1; o < 64; o <<= 1) { float t = __shfl_up(v, o); if (lane >= o) v += t; }
        cum[lane] = v;
        if (lane == 63) asum[(b * NC + c) * NH + h] = v;
    }
    __syncthreads();

    const float cum63 = cum[63];
#pragma unroll
    for (int q = 0; q < 16; q++) {
        int i = q * 4 + wv;
        float dcfi = __expf(cum63 - cum[i]) * dts[i];
        xsc[lane * 72 + i] = (__bf16)((float)xT[lane * 72 + i] * dcfi);
    }
    __syncthreads();

    f32x4 z4 = {0.f, 0.f, 0.f, 0.f};
    f32x4 accS[8];
#pragma unroll
    for (int nt = 0; nt < 8; nt++) accS[nt] = z4;
#pragma unroll
    for (int ks = 0; ks < 2; ks++) {
        bf16x8 a = *(const bf16x8*)&xsc[(wv * 16 + lrow) * 72 + ks * 32 + lko];
#pragma unroll
        for (int nt = 0; nt < 8; nt++) {
            bf16x8 bb = *(const bf16x8*)&BT[(nt * 16 + lrow) * 72 + ks * 32 + lko];
            accS[nt] = __builtin_amdgcn_mfma_f32_16x16x32_bf16(a, bb, accS[nt], 0, 0, 0);
        }
    }
    __bf16* sp = states + ((size_t)(b * NC + c) * NH + h) * 8192;
#pragma unroll
    for (int nt = 0; nt < 8; nt++)
#pragma unroll
        for (int r = 0; r < 4; r++) {
            int p = wv * 16 + (lane >> 4) * 4 + r;
            int n = nt * 16 + lrow;
            sp[p * 128 + n] = (__bf16)accS[nt][r];
        }
}

// ---------------- inter-chunk scan (4-deep load prefetch, in-place) ----------------
__global__ __launch_bounds__(256) void k_scan(__bf16* __restrict__ states, const float* __restrict__ asum) {
    const int seg = blockIdx.x, h = blockIdx.y, b = blockIdx.z;
    __shared__ float efs[NC];
    if (threadIdx.x < NC) efs[threadIdx.x] = __expf(asum[(b * NC + threadIdx.x) * NH + h]);
    __syncthreads();
    const int e0 = seg * 1024 + threadIdx.x * 4;
    __bf16* base = states + ((size_t)(b * NC) * NH + h) * 8192 + e0;
    const size_t cs = (size_t)NH * 8192;
    float S[4] = {0.f, 0.f, 0.f, 0.f};
    s16x4 r0 = *(const s16x4*)(base);
    s16x4 r1 = *(const s16x4*)(base + cs);
    s16x4 r2 = *(const s16x4*)(base + 2 * cs);
    s16x4 r3;
#define SCAN_STEP(RV, CC)                                                                  \
    {                                                                                      \
        s16x4 o; float e = efs[CC];                                                        \
        _Pragma("unroll")                                                                  \
        for (int q = 0; q < 4; q++) {                                                      \
            float t = (float)__builtin_bit_cast(__bf16, (short)RV[q]);                     \
            o[q] = __builtin_bit_cast(short, (__bf16)S[q]);                                \
            S[q] = e * S[q] + t;                                                           \
        }                                                                                  \
        *(s16x4*)(base + (size_t)(CC) * cs) = o;                                           \
    }
    for (int c = 0; c < NC; c += 4) {
        r3 = *(const s16x4*)(base + (size_t)(c + 3) * cs);
        SCAN_STEP(r0, c);
        if (c + 4 < NC) r0 = *(const s16x4*)(base + (size_t)(c + 4) * cs);
        SCAN_STEP(r1, c + 1);
        if (c + 5 < NC) r1 = *(const s16x4*)(base + (size_t)(c + 5) * cs);
        SCAN_STEP(r2, c + 2);
        if (c + 6 < NC) r2 = *(const s16x4*)(base + (size_t)(c + 6) * cs);
        SCAN_STEP(r3, c + 3);
    }
#undef SCAN_STEP
}

// ---------------- SSD part B (MFMA, merged): Y = (M+D·I)@x + exp(cum)*(C@Sprev^T) ----------------
__global__ __launch_bounds__(256) void k_ssd_b(const __bf16* __restrict__ xconv, const float* __restrict__ dtbuf,
                                               const __bf16* __restrict__ states, const float* __restrict__ A_log,
                                               const float* __restrict__ cbt, const float* __restrict__ D_param,
                                               __bf16* __restrict__ ybuf) {
    const int h = blockIdx.x, c = blockIdx.y, b = blockIdx.z;
    const int tid = threadIdx.x, wv = tid >> 6, lane = tid & 63;
    const int lrow = lane & 15, lko = (lane >> 4) * 8;
    __shared__ __align__(16) __bf16 xT[64 * 72];
    __shared__ __align__(16) __bf16 Ms[64 * 72];
    __shared__ __align__(16) __bf16 Csh[64 * 136];
    __shared__ __align__(16) __bf16 Sps[64 * 136];
    __shared__ float dts[64], cum[64];

    const float Ah = -__expf(A_log[h]);
    const size_t rowbase = (size_t)b * L_ + c * CHUNK;
    const __bf16* sp = states + ((size_t)(b * NC + c) * NH + h) * 8192;
#pragma unroll
    for (int q = 0; q < 32; q++) {
        int i = q * 2 + (wv >> 1);
        int n = (wv & 1) * 64 + lane;
        Csh[i * 136 + n] = xconv[(rowbase + i) * CD + DI + DS + n];
        Sps[i * 136 + n] = sp[i * 128 + n];
    }
#pragma unroll
    for (int q = 0; q < 16; q++) {
        int i = q * 4 + wv;
        xT[lane * 72 + i] = xconv[(rowbase + i) * CD + h * HD + lane];
    }
    if (wv == 0) {
        float dtv = dtbuf[(rowbase + lane) * NH + h];
        dts[lane] = dtv;
        float v = Ah * dtv;
#pragma unroll
        for (int o = 1; o < 64; o <<= 1) { float t = __shfl_up(v, o); if (lane >= o) v += t; }
        cum[lane] = v;
    }
    __syncthreads();

    const float Dh = D_param[h];
    const float* cbt_bc = cbt + (size_t)(b * NC + c) * 4096;
#pragma unroll
    for (int q = 0; q < 16; q++) {
        int i = q * 4 + wv, j = lane;
        float m = 0.f;
        if (j <= i) m = cbt_bc[i * 64 + j] * __expf(cum[i] - cum[j]) * dts[j];
        if (j == i) m += Dh;
        Ms[i * 72 + j] = (__bf16)m;
    }
    __syncthreads();

    f32x4 z4 = {0.f, 0.f, 0.f, 0.f};
    f32x4 accY[4], accO[4];
#pragma unroll
    for (int pt = 0; pt < 4; pt++) { accY[pt] = z4; accO[pt] = z4; }
#pragma unroll
    for (int ks = 0; ks < 2; ks++) {
        bf16x8 a = *(const bf16x8*)&Ms[(wv * 16 + lrow) * 72 + ks * 32 + lko];
#pragma unroll
        for (int pt = 0; pt < 4; pt++) {
            bf16x8 bb = *(const bf16x8*)&xT[(pt * 16 + lrow) * 72 + ks * 32 + lko];
            accY[pt] = __builtin_amdgcn_mfma_f32_16x16x32_bf16(a, bb, accY[pt], 0, 0, 0);
        }
    }
#pragma unroll
    for (int ks = 0; ks < 4; ks++) {
        bf16x8 a = *(const bf16x8*)&Csh[(wv * 16 + lrow) * 136 + ks * 32 + lko];
#pragma unroll
        for (int pt = 0; pt < 4; pt++) {
            bf16x8 bb = *(const bf16x8*)&Sps[(pt * 16 + lrow) * 136 + ks * 32 + lko];
            accO[pt] = __builtin_amdgcn_mfma_f32_16x16x32_bf16(a, bb, accO[pt], 0, 0, 0);
        }
    }
#pragma unroll
    for (int r = 0; r < 4; r++) {
        int i = wv * 16 + (lane >> 4) * 4 + r;
        float ef = __expf(cum[i]);
#pragma unroll
        for (int pt = 0; pt < 4; pt++) {
            size_t idx = (rowbase + i) * DI + h * HD + pt * 16 + lrow;
            ybuf[idx] = (__bf16)(accY[pt][r] + ef * accO[pt][r]);
        }
    }
}

// ---------------- gate (silu(z)) + RMSNorm -> bf16 (short8 vectorized) ----------------
__global__ __launch_bounds__(256) void k_gate_norm(const __bf16* __restrict__ ybuf, const __bf16* __restrict__ zbuf,
                                                   const float* __restrict__ norm_w, __bf16* __restrict__ ybf) {
    const int r = blockIdx.x;
    const int tid = threadIdx.x;
    const int col0 = tid * 8;
    s16x8 y8 = *(const s16x8*)(ybuf + (size_t)r * DI + col0);
    s16x8 z8 = *(const s16x8*)(zbuf + (size_t)r * DI + col0);
    float v[8];
    float ss = 0.f;
#pragma unroll
    for (int q = 0; q < 8; q++) {
        float y = (float)__builtin_bit_cast(__bf16, (short)y8[q]);
        float z = (float)__builtin_bit_cast(__bf16, (short)z8[q]);
        float g = z * __builtin_amdgcn_rcpf(1.f + __expf(-z));
        v[q] = y * g;
        ss += v[q] * v[q];
    }
#pragma unroll
    for (int o = 32; o > 0; o >>= 1) ss += __shfl_down(ss, o);
    __shared__ float wsum[4];
    __shared__ float rmss;
    if ((tid & 63) == 0) wsum[tid >> 6] = ss;
    __syncthreads();
    if (tid == 0) {
        float t = wsum[0] + wsum[1] + wsum[2] + wsum[3];
        rmss = rsqrtf(t / (float)DI + 1e-5f);
    }
    __syncthreads();
    float rm = rmss;
    s16x8 o8;
#pragma unroll
    for (int q = 0; q < 8; q++)
        o8[q] = __builtin_bit_cast(short, (__bf16)(v[q] * rm * norm_w[col0 + q]));
    *(s16x8*)(ybf + (size_t)r * DI + col0) = o8;
}

// ---------------- launcher ----------------
extern "C" void kernel_launch(void* const* d_in, const int* in_sizes, int n_in,
                              void* d_out, int out_size, void* d_ws, size_t ws_size,
                              hipStream_t stream) {
    const float* u       = (const float*)d_in[0];
    const float* W_in    = (const float*)d_in[1];
    const float* conv_w  = (const float*)d_in[2];
    const float* conv_b  = (const float*)d_in[3];
    const float* dt_bias = (const float*)d_in[4];
    const float* A_log   = (const float*)d_in[5];
    const float* D_param = (const float*)d_in[6];
    const float* norm_w  = (const float*)d_in[7];
    const float* W_out   = (const float*)d_in[8];
    float* out = (float*)d_out;

    // ---- static workspace plan (145.8 MB total) ----
    constexpr size_t OFF_WOBF  = 0;
    constexpr size_t OFF_ZBUF  = 4194304;
    constexpr size_t OFF_DT    = 37748736;
    constexpr size_t OFF_ASUM  = 38797312;
    constexpr size_t OFF_XCONV = 38813696;
    constexpr size_t OFF_CBT   = 76562432;
    constexpr size_t OFF_BIG   = 78659584;
    constexpr size_t NEED      = 145768448;
    if (ws_size < NEED) return;

    char* ws = (char*)d_ws;
    __bf16* wobf   = (__bf16*)(ws + OFF_WOBF);
    __bf16* zbuf   = (__bf16*)(ws + OFF_ZBUF);
    float*  dtbuf  = (float*) (ws + OFF_DT);
    float*  asum   = (float*) (ws + OFF_ASUM);
    __bf16* xconv  = (__bf16*)(ws + OFF_XCONV);
    float*  cbt    = (float*) (ws + OFF_CBT);
    __bf16* ubf    = (__bf16*)(ws + OFF_BIG);
    __bf16* wibf   = (__bf16*)(ws + OFF_BIG + 16777216);
    __bf16* xbcraw = (__bf16*)(ws + OFF_BIG + 16777216 + 9437184);
    __bf16* states = (__bf16*)(ws + OFF_BIG);          // reuses ubf/wibf/xbcraw after conv
    __bf16* ybf    = (__bf16*)(ws + OFF_XCONV);        // reuses xconv after ssd_b
    __bf16* ybuf   = (__bf16*)d_out;                   // bf16 scratch, overwritten by gemm2

    (void)hipFuncSetAttribute((const void*)k_gemm1, hipFuncAttributeMaxDynamicSharedMemorySize, 32768);
    (void)hipFuncSetAttribute((const void*)k_gemm2, hipFuncAttributeMaxDynamicSharedMemorySize, 32768);

    // fused converts: u -> ubf, W_in -> wibf (padded), W_out -> wobf
    constexpr int QTOT = ROWS * DM / 4 + NPAD2 * DM / 4 + DM * DI / 4;
    k_convert_all<<<(QTOT + 255) / 256, 256, 0, stream>>>(u, W_in, W_out, ubf, wibf, wobf);

    k_gemm1<<<2240, 512, 32768, stream>>>(ubf, wibf, zbuf, xbcraw, dtbuf, dt_bias);
    k_conv<<<dim3(9, 128), 256, 0, stream>>>(xbcraw, conv_w, conv_b, xconv);
    k_cbt<<<dim3(NC, B_), 256, 0, stream>>>(xconv, cbt);
    k_ssd_a<<<dim3(NH, NC, B_), 256, 0, stream>>>(xconv, dtbuf, A_log, states, asum);
    k_scan<<<dim3(8, NH, B_), 256, 0, stream>>>(states, asum);
    k_ssd_b<<<dim3(NH, NC, B_), 256, 0, stream>>>(xconv, dtbuf, states, A_log, cbt, D_param, ybuf);
    k_gate_norm<<<ROWS, 256, 0, stream>>>(ybuf, zbuf, norm_w, ybf);
    k_gemm2<<<512, 512, 32768, stream>>>(ybf, wobf, out);
}